// Round 3
// baseline (320.986 us; speedup 1.0000x reference)
//
#include <hip/hip_runtime.h>
#include <hip/hip_bf16.h>
#include <stdint.h>

typedef unsigned short u16;
typedef __attribute__((ext_vector_type(8))) short short8_t;
typedef __attribute__((ext_vector_type(4))) float f32x4;

#define D_DIM 512
#define K_CL  256
#define STEPS 16   // D_DIM / 32

__device__ __forceinline__ u16 f2bf(float f) {
  union { float f; uint32_t u; } v; v.f = f;
  uint32_t r = v.u + 0x7fffu + ((v.u >> 16) & 1u);  // RNE
  return (u16)(r >> 16);
}

// prep: clusters fp32 [256][512] -> bf16 cb [256][512] + csq[256] (fp32 norms)
__global__ void prep_kernel(const float* __restrict__ clusters,
                            u16* __restrict__ cb, float* __restrict__ csq) {
  int k = blockIdx.x;
  int t = threadIdx.x;  // 128 threads, 4 floats each
  float4 f = ((const float4*)(clusters + (size_t)k * D_DIM))[t];
  ushort4 u;
  u.x = f2bf(f.x); u.y = f2bf(f.y); u.z = f2bf(f.z); u.w = f2bf(f.w);
  ((ushort4*)(cb + (size_t)k * D_DIM))[t] = u;
  float s = f.x*f.x + f.y*f.y + f.z*f.z + f.w*f.w;
  #pragma unroll
  for (int m = 1; m < 64; m <<= 1) s += __shfl_xor(s, m, 64);
  __shared__ float part[2];
  if ((t & 63) == 0) part[t >> 6] = s;
  __syncthreads();
  if (t == 0) csq[k] = part[0] + part[1];
}

// Barrier-free main loop: block = 4 waves = 2 row-stripes x 2 col-halves.
// Each wave: 32 rows x 128 cols, A (x/HBM) and B (cb/L2) fragments loaded
// straight to registers, acc in AGPRs. No LDS until the epilogue row-norm.
__global__ __launch_bounds__(256)
void cluster_kernel(const float* __restrict__ x,
                    const u16* __restrict__ cb,
                    const float* __restrict__ csq,
                    float* __restrict__ out) {
  __shared__ float rowsum[2][2][32];   // [stripe][half][row] — epilogue only

  const int tid    = threadIdx.x;
  const int lane   = tid & 63;
  const int w      = tid >> 6;
  const int stripe = w >> 1;        // 0..1 (32-row group)
  const int half   = w & 1;         // 0..1 (128-col group)
  const int quad   = lane >> 4;
  const int l16    = lane & 15;
  const int row0   = blockIdx.x * 64 + stripe * 32;

  // A: lane loads rows (row0 + l16) [mi=0] and (row0 + 16 + l16) [mi=1],
  // k-chunk quad*8..quad*8+8 of each 32-k slab; step offsets are immediates.
  const float* xg0 = x + (size_t)(row0 + l16) * D_DIM + quad * 8;
  const float* xg1 = xg0 + 16 * D_DIM;

  // B: 8 per-lane base pointers, col = half*128 + ni*16 + l16, k-chunk quad*8.
  const u16* bg[8];
  #pragma unroll
  for (int ni = 0; ni < 8; ++ni)
    bg[ni] = cb + (size_t)(half * 128 + ni * 16 + l16) * D_DIM + quad * 8;

  f32x4 acc[2][8];
  #pragma unroll
  for (int mi = 0; mi < 2; ++mi)
    #pragma unroll
    for (int ni = 0; ni < 8; ++ni)
      acc[mi][ni] = (f32x4){0.f, 0.f, 0.f, 0.f};

  float sq0 = 0.f, sq1 = 0.f;

  // register ping-pong pipeline (1 step ahead), no barriers anywhere
  short8_t Bp[2][8];
  float4   Ap[2][4];
  #pragma unroll
  for (int ni = 0; ni < 8; ++ni) Bp[0][ni] = *(const short8_t*)(bg[ni]);
  Ap[0][0] = *(const float4*)(xg0);
  Ap[0][1] = *(const float4*)(xg0 + 4);
  Ap[0][2] = *(const float4*)(xg1);
  Ap[0][3] = *(const float4*)(xg1 + 4);

  #pragma unroll
  for (int k = 0; k < STEPS; ++k) {
    const int cur = k & 1, nxt = cur ^ 1;
    if (k < STEPS - 1) {   // issue step k+1 (immediate offsets: (k+1)*32 elems)
      #pragma unroll
      for (int ni = 0; ni < 8; ++ni)
        Bp[nxt][ni] = *(const short8_t*)(bg[ni] + (k + 1) * 32);
      Ap[nxt][0] = *(const float4*)(xg0 + (k + 1) * 32);
      Ap[nxt][1] = *(const float4*)(xg0 + (k + 1) * 32 + 4);
      Ap[nxt][2] = *(const float4*)(xg1 + (k + 1) * 32);
      Ap[nxt][3] = *(const float4*)(xg1 + (k + 1) * 32 + 4);
    }
    // convert A(k) fp32 -> bf16 frags; accumulate row norms from fp32
    short8_t aF0, aF1;
    {
      float4 f0 = Ap[cur][0], f1 = Ap[cur][1];
      sq0 += f0.x*f0.x + f0.y*f0.y + f0.z*f0.z + f0.w*f0.w
           + f1.x*f1.x + f1.y*f1.y + f1.z*f1.z + f1.w*f1.w;
      union { u16 u[8]; short8_t v; } pk;
      pk.u[0]=f2bf(f0.x); pk.u[1]=f2bf(f0.y); pk.u[2]=f2bf(f0.z); pk.u[3]=f2bf(f0.w);
      pk.u[4]=f2bf(f1.x); pk.u[5]=f2bf(f1.y); pk.u[6]=f2bf(f1.z); pk.u[7]=f2bf(f1.w);
      aF0 = pk.v;
    }
    {
      float4 f0 = Ap[cur][2], f1 = Ap[cur][3];
      sq1 += f0.x*f0.x + f0.y*f0.y + f0.z*f0.z + f0.w*f0.w
           + f1.x*f1.x + f1.y*f1.y + f1.z*f1.z + f1.w*f1.w;
      union { u16 u[8]; short8_t v; } pk;
      pk.u[0]=f2bf(f0.x); pk.u[1]=f2bf(f0.y); pk.u[2]=f2bf(f0.z); pk.u[3]=f2bf(f0.w);
      pk.u[4]=f2bf(f1.x); pk.u[5]=f2bf(f1.y); pk.u[6]=f2bf(f1.z); pk.u[7]=f2bf(f1.w);
      aF1 = pk.v;
    }
    #pragma unroll
    for (int ni = 0; ni < 8; ++ni) {
      acc[0][ni] = __builtin_amdgcn_mfma_f32_16x16x32_bf16(aF0, Bp[cur][ni], acc[0][ni], 0, 0, 0);
      acc[1][ni] = __builtin_amdgcn_mfma_f32_16x16x32_bf16(aF1, Bp[cur][ni], acc[1][ni], 0, 0, 0);
    }
  }

  // x_sq: reduce partials across quads (lanes l16, 16+l16, 32+l16, 48+l16)
  sq0 += __shfl_xor(sq0, 16, 64); sq0 += __shfl_xor(sq0, 32, 64);
  sq1 += __shfl_xor(sq1, 16, 64); sq1 += __shfl_xor(sq1, 32, 64);
  // now every lane holds xsq[row l16] (mi0) and xsq[row 16+l16] (mi1)

  // cluster norms for this wave's 8 column groups
  float cs[8];
  #pragma unroll
  for (int ni = 0; ni < 8; ++ni) cs[ni] = csq[half * 128 + ni * 16 + l16];

  // Student-t + per-row half-sums
  #pragma unroll
  for (int mi = 0; mi < 2; ++mi) {
    #pragma unroll
    for (int v = 0; v < 4; ++v) {
      const int r = quad * 4 + v;               // row-within-16 (C-layout)
      const float xs = __shfl(mi == 0 ? sq0 : sq1, r, 64);
      float s = 0.f;
      #pragma unroll
      for (int ni = 0; ni < 8; ++ni) {
        float d = xs + cs[ni] - 2.0f * acc[mi][ni][v];
        d = fmaxf(d, 0.f);
        float q = 1.0f / (1.0f + d);            // alpha=1
        acc[mi][ni][v] = q;
        s += q;
      }
      s += __shfl_xor(s, 1, 64);
      s += __shfl_xor(s, 2, 64);
      s += __shfl_xor(s, 4, 64);
      s += __shfl_xor(s, 8, 64);
      if (l16 == 0) rowsum[stripe][half][mi * 16 + r] = s;
    }
  }
  __syncthreads();

  // normalize (combine the two col-halves) + non-temporal store
  #pragma unroll
  for (int mi = 0; mi < 2; ++mi) {
    #pragma unroll
    for (int v = 0; v < 4; ++v) {
      const int r = mi * 16 + quad * 4 + v;
      const float inv = 1.0f / (rowsum[stripe][0][r] + rowsum[stripe][1][r]);
      float* orow = out + (size_t)(row0 + r) * K_CL + half * 128;
      #pragma unroll
      for (int ni = 0; ni < 8; ++ni)
        __builtin_nontemporal_store(acc[mi][ni][v] * inv, orow + ni * 16 + l16);
    }
  }
}

extern "C" void kernel_launch(void* const* d_in, const int* in_sizes, int n_in,
                              void* d_out, int out_size, void* d_ws, size_t ws_size,
                              hipStream_t stream) {
  const float* x        = (const float*)d_in[0];
  const float* clusters = (const float*)d_in[1];
  float* out = (float*)d_out;
  const int N = in_sizes[0] / D_DIM;   // 65536

  u16*   cb  = (u16*)d_ws;                                   // 256 KB
  float* csq = (float*)((char*)d_ws + (size_t)K_CL * D_DIM * sizeof(u16));

  prep_kernel<<<K_CL, 128, 0, stream>>>(clusters, cb, csq);
  cluster_kernel<<<N / 64, 256, 0, stream>>>(x, cb, csq, out);
}

// Round 4
// 232.314 us; speedup vs baseline: 1.3817x; 1.3817x over previous
//
#include <hip/hip_runtime.h>
#include <hip/hip_bf16.h>
#include <stdint.h>

typedef unsigned short u16;
typedef __attribute__((ext_vector_type(8))) short short8_t;
typedef __attribute__((ext_vector_type(4))) float f32x4;

#define D_DIM 512
#define K_CL  256
#define BM    64
#define NITER 16   // D_DIM / 32

__device__ __forceinline__ u16 f2bf(float f) {
  union { float f; uint32_t u; } v; v.f = f;
  uint32_t r = v.u + 0x7fffu + ((v.u >> 16) & 1u);  // RNE
  return (u16)(r >> 16);
}

// prep: clusters fp32 [256][512] -> bf16 cb [256][512] + csq[256] (fp32 norms)
__global__ void prep_kernel(const float* __restrict__ clusters,
                            u16* __restrict__ cb, float* __restrict__ csq) {
  int k = blockIdx.x;
  int t = threadIdx.x;  // 128 threads, 4 floats each
  float4 f = ((const float4*)(clusters + (size_t)k * D_DIM))[t];
  ushort4 u;
  u.x = f2bf(f.x); u.y = f2bf(f.y); u.z = f2bf(f.z); u.w = f2bf(f.w);
  ((ushort4*)(cb + (size_t)k * D_DIM))[t] = u;
  float s = f.x*f.x + f.y*f.y + f.z*f.z + f.w*f.w;
  #pragma unroll
  for (int m = 1; m < 64; m <<= 1) s += __shfl_xor(s, m, 64);
  __shared__ float part[2];
  if ((t & 63) == 0) part[t >> 6] = s;
  __syncthreads();
  if (t == 0) csq[k] = part[0] + part[1];
}

// R1 structure, retuned for TLP: 64-row x 256-col tile, 256 threads (4 waves),
// grid 1024 = 4 independent blocks/CU. 2-barrier K-loop, A reg-prefetch 1 ahead.
// wave w owns cols [w*64, w*64+64); all waves share the A rows.
__global__ __launch_bounds__(256, 4)
void cluster_kernel(const float* __restrict__ x,
                    const u16* __restrict__ cb,
                    const float* __restrict__ csq,
                    float* __restrict__ out) {
  __shared__ u16  lA[BM * 32];        // 4 KB
  __shared__ u16  lB[K_CL * 32];      // 16 KB
  __shared__ float xsq_lds[BM];
  __shared__ float csq_lds[K_CL];
  __shared__ float rowsum[4 * BM];    // 1 KB   (total LDS ~22.8 KB)

  const int tid  = threadIdx.x;
  const int lane = tid & 63;
  const int w    = tid >> 6;          // wave id = column quarter
  const int quad = lane >> 4;
  const int l16  = lane & 15;
  const int row0 = blockIdx.x * BM;

  csq_lds[tid] = csq[tid];            // 256 threads, 256 clusters

  // A staging: thread -> (row ar, 8-float chunk jga); 32 k-elems per iter
  const int ar  = tid >> 2;           // 0..63
  const int jga = tid & 3;            // 0..3
  const float* xg = x + (size_t)(row0 + ar) * D_DIM + jga * 8;
  short8_t* aw = (short8_t*)&lA[ar * 32 + jga * 8];

  // B staging: 4 global_load_lds per thread; issue i covers cols i*64..i*64+63
  // src_i = cb + (i*64 + ar)*512 + jga*8  -> lB byte offset (i*256+tid)*16
  const u16* bsrc0 = cb + (size_t)ar * D_DIM + jga * 8;

  f32x4 acc[4][4];
  #pragma unroll
  for (int i = 0; i < 4; ++i)
    #pragma unroll
    for (int j = 0; j < 4; ++j)
      acc[i][j] = (f32x4){0.f, 0.f, 0.f, 0.f};

  float sq = 0.f;

  // prologue: A(0) register prefetch
  float4 f0 = *(const float4*)(xg);
  float4 f1 = *(const float4*)(xg + 4);

  #pragma unroll 1
  for (int k = 0; k < NITER; ++k) {
    const int kk = k * 32;

    // issue B(k) first (L2-resident; latency overlaps the A convert below)
    #pragma unroll
    for (int i = 0; i < 4; ++i)
      __builtin_amdgcn_global_load_lds(
          (const __attribute__((address_space(1))) void*)(bsrc0 + i * (64 * D_DIM) + kk),
          (__attribute__((address_space(3))) void*)((char*)lB + (i * 256 + tid) * 16),
          16, 0, 0);

    // convert A(k) (already in f0/f1) -> bf16 -> LDS; accumulate row norm fp32
    {
      sq += f0.x*f0.x + f0.y*f0.y + f0.z*f0.z + f0.w*f0.w
          + f1.x*f1.x + f1.y*f1.y + f1.z*f1.z + f1.w*f1.w;
      union { u16 u[8]; short8_t v; } pk;
      pk.u[0]=f2bf(f0.x); pk.u[1]=f2bf(f0.y); pk.u[2]=f2bf(f0.z); pk.u[3]=f2bf(f0.w);
      pk.u[4]=f2bf(f1.x); pk.u[5]=f2bf(f1.y); pk.u[6]=f2bf(f1.z); pk.u[7]=f2bf(f1.w);
      *aw = pk.v;
    }

    // prefetch A(k+1); its latency is hidden behind this iter's barrier+MFMA
    if (k < NITER - 1) {
      f0 = *(const float4*)(xg + kk + 32);
      f1 = *(const float4*)(xg + kk + 36);
    }

    __syncthreads();   // staging (ds_write + global_load_lds) complete

    // fragments + 16 MFMA (bF read folded into ni loop to cap live regs)
    short8_t aF[4];
    #pragma unroll
    for (int mi = 0; mi < 4; ++mi)
      aF[mi] = *(const short8_t*)&lA[(mi * 16 + l16) * 32 + quad * 8];
    #pragma unroll
    for (int ni = 0; ni < 4; ++ni) {
      short8_t bF = *(const short8_t*)&lB[(w * 64 + ni * 16 + l16) * 32 + quad * 8];
      #pragma unroll
      for (int mi = 0; mi < 4; ++mi)
        acc[mi][ni] = __builtin_amdgcn_mfma_f32_16x16x32_bf16(
            aF[mi], bF, acc[mi][ni], 0, 0, 0);
    }

    if (k < NITER - 1) __syncthreads();   // frags consumed; buffers reusable
  }

  // x_sq: combine the 4 staging lanes (consecutive tids) of each row
  sq += __shfl_xor(sq, 1, 64);
  sq += __shfl_xor(sq, 2, 64);
  if ((tid & 3) == 0) xsq_lds[ar] = sq;
  __syncthreads();

  // epilogue: Student-t + per-row partial sums
  #pragma unroll
  for (int mi = 0; mi < 4; ++mi) {
    #pragma unroll
    for (int v = 0; v < 4; ++v) {
      int row = mi * 16 + quad * 4 + v;
      float xs = xsq_lds[row];
      float s = 0.f;
      #pragma unroll
      for (int ni = 0; ni < 4; ++ni) {
        float d = xs + csq_lds[w * 64 + ni * 16 + l16] - 2.0f * acc[mi][ni][v];
        d = fmaxf(d, 0.f);
        float q = 1.0f / (1.0f + d);   // alpha=1: (1+d^2)^-1
        acc[mi][ni][v] = q;
        s += q;
      }
      s += __shfl_xor(s, 1, 64);
      s += __shfl_xor(s, 2, 64);
      s += __shfl_xor(s, 4, 64);
      s += __shfl_xor(s, 8, 64);
      if (l16 == 0) rowsum[w * 64 + row] = s;
    }
  }
  __syncthreads();

  // normalize + store (non-temporal: keep out of L2/LLC, x benefits from residency)
  #pragma unroll
  for (int mi = 0; mi < 4; ++mi) {
    #pragma unroll
    for (int v = 0; v < 4; ++v) {
      int row = mi * 16 + quad * 4 + v;
      float tot = rowsum[row] + rowsum[64 + row] + rowsum[128 + row] + rowsum[192 + row];
      float inv = 1.0f / tot;
      float* orow = out + (size_t)(row0 + row) * K_CL;
      #pragma unroll
      for (int ni = 0; ni < 4; ++ni)
        __builtin_nontemporal_store(acc[mi][ni][v] * inv,
                                    orow + w * 64 + ni * 16 + l16);
    }
  }
}

extern "C" void kernel_launch(void* const* d_in, const int* in_sizes, int n_in,
                              void* d_out, int out_size, void* d_ws, size_t ws_size,
                              hipStream_t stream) {
  const float* x        = (const float*)d_in[0];
  const float* clusters = (const float*)d_in[1];
  float* out = (float*)d_out;
  const int N = in_sizes[0] / D_DIM;   // 65536

  u16*   cb  = (u16*)d_ws;                                   // 256 KB
  float* csq = (float*)((char*)d_ws + (size_t)K_CL * D_DIM * sizeof(u16));

  prep_kernel<<<K_CL, 128, 0, stream>>>(clusters, cb, csq);
  cluster_kernel<<<N / BM, 256, 0, stream>>>(x, cb, csq, out);
}